// Round 1
// baseline (129.135 us; speedup 1.0000x reference)
//
#include <hip/hip_runtime.h>
#include <math.h>

#define NDIM   16
#define NPAIR  136
#define NTRIP  816
#define NCOL   985   // 1 + 16 + 136 + 816 + 16
#define GROUPS 8
#define ROWS_PER_BLOCK (4 * GROUPS)   // 4 waves/block, 1 row per wave per group

__global__ __launch_bounds__(256) void sindy_kernel(
    const float* __restrict__ z, const float* __restrict__ dz,
    float* __restrict__ out, int batch)
{
    __shared__ unsigned short table[NPAIR + NTRIP];  // packed i | j<<4 | k<<8
    __shared__ float zbuf[4][NDIM];

    // Cooperatively build the combinatorial index table (row-independent).
    for (int e = threadIdx.x; e < NPAIR + NTRIP; e += blockDim.x) {
        unsigned short pk;
        if (e < NPAIR) {
            int p = e, i = 0;
            while (p >= NDIM - i) { p -= NDIM - i; ++i; }
            int j = i + p;
            pk = (unsigned short)(i | (j << 4));
        } else {
            int t = e - NPAIR, i = 0;
            for (;;) {
                int cnt = (NDIM - i) * (NDIM - i + 1) / 2;  // triples starting at i
                if (t < cnt) break;
                t -= cnt; ++i;
            }
            int j = i;
            while (t >= NDIM - j) { t -= NDIM - j; ++j; }
            int k = j + t;
            pk = (unsigned short)(i | (j << 4) | (k << 8));
        }
        table[e] = pk;
    }
    __syncthreads();

    const int wid  = threadIdx.x >> 6;   // wave id 0..3 -> row within group
    const int lane = threadIdx.x & 63;

    const int row0 = blockIdx.x * ROWS_PER_BLOCK;
    for (int g = 0; g < GROUPS; ++g) {
        const int rowbase = row0 + g * 4;

        __syncthreads();  // zbuf from previous group no longer needed
        if (threadIdx.x < 64) {
            int r = threadIdx.x >> 4;
            int c = threadIdx.x & 15;
            int row = rowbase + r;
            float v = 0.f;
            if (row < batch) v = (c < 8) ? z[row * 8 + c] : dz[row * 8 + (c - 8)];
            zbuf[r][c] = v;
        }
        __syncthreads();

        const int row = rowbase + wid;
        if (row < batch) {
            float* __restrict__ orow = out + (size_t)row * NCOL;
            const float* zr = zbuf[wid];
            #pragma unroll
            for (int it = 0; it < 16; ++it) {
                int col = it * 64 + lane;
                if (col < NCOL) {
                    float v;
                    if (col == 0) {
                        v = 1.0f;
                    } else if (col < 1 + NDIM) {
                        v = zr[col - 1];
                    } else if (col < 1 + NDIM + NPAIR) {
                        unsigned pk = table[col - (1 + NDIM)];
                        v = zr[pk & 15] * zr[(pk >> 4) & 15];
                    } else if (col < 1 + NDIM + NPAIR + NTRIP) {
                        unsigned pk = table[NPAIR + (col - (1 + NDIM + NPAIR))];
                        v = zr[pk & 15] * zr[(pk >> 4) & 15] * zr[(pk >> 8) & 15];
                    } else {
                        v = sinf(zr[col - (1 + NDIM + NPAIR + NTRIP)]);
                    }
                    orow[col] = v;
                }
            }
        }
    }
}

extern "C" void kernel_launch(void* const* d_in, const int* in_sizes, int n_in,
                              void* d_out, int out_size, void* d_ws, size_t ws_size,
                              hipStream_t stream) {
    const float* z  = (const float*)d_in[0];
    const float* dz = (const float*)d_in[1];
    float* out = (float*)d_out;
    const int batch = in_sizes[0] / 8;  // LATENT_DIM = 8

    const int blocks = (batch + ROWS_PER_BLOCK - 1) / ROWS_PER_BLOCK;
    sindy_kernel<<<blocks, 256, 0, stream>>>(z, dz, out, batch);
}